// Round 2
// baseline (340.839 us; speedup 1.0000x reference)
//
#include <hip/hip_runtime.h>
#include <cstdint>

#define DEVINL __device__ __forceinline__

typedef __attribute__((ext_vector_type(8))) short short8;       // 8 x bf16 (4 VGPRs)
typedef __attribute__((ext_vector_type(4))) short short4v;      // 4 x bf16 (2 VGPRs)
typedef __attribute__((ext_vector_type(4))) float floatx4;
typedef __attribute__((ext_vector_type(4))) unsigned short ushort4v;

// hardware packed cvt: D = {bf16(a), bf16(b)} (RNE) — use ONLY for true pair
// packs (scalar use regressed R7: asm blocks CSE, +20 VGPR in GEMM epilogue).
DEVINL uint32_t pkbf(float a, float b) {
  uint32_t d;
  asm("v_cvt_pk_bf16_f32 %0, %1, %2" : "=v"(d) : "v"(a), "v"(b));
  return d;
}
// software RNE fp32->bf16 for scalar stores (compiler-schedulable)
DEVINL unsigned short f2bf(float f) {
  union { float f; uint32_t u; } v; v.f = f;
  return (unsigned short)((v.u + 0x7fffu + ((v.u >> 16) & 1u)) >> 16);
}
DEVINL float bf2f(unsigned short h) {
  union { uint32_t u; float f; } v; v.u = ((uint32_t)h) << 16;
  return v.f;
}

#if defined(__has_builtin) && __has_builtin(__builtin_amdgcn_exp2f)
#define EXP2(x) __builtin_amdgcn_exp2f(x)
#else
#define EXP2(x) exp2f(x)
#endif

// fast GELU (tanh form, exp2-based): max |err| ~3e-4 vs exact erf GELU.
DEVINL float fast_gelu(float v) {
  const float z = -2.30220795f * v * (1.0f + 0.044715f * v * v);
  return v * __builtin_amdgcn_rcpf(1.0f + EXP2(z));
}

typedef __attribute__((address_space(3))) unsigned char* lds_ptr_t;
typedef const __attribute__((address_space(1))) unsigned char* gbl_ptr_t;
// async global->LDS, 16B per lane; LDS dest = wave-uniform base + lane*16
DEVINL void load_lds_128(const void* g, void* l) {
  __builtin_amdgcn_global_load_lds((gbl_ptr_t)g, (lds_ptr_t)l, 16, 0, 0);
}

// inline-asm LDS read: OPAQUE to the waitcnt legalizer. R1 post-mortem: plain
// C ds_reads after global_load_lds get a compiler-inserted s_waitcnt vmcnt(0)
// (LDS-DMA MayAlias) which drains the prefetch queue EVERY phase — the whole
// point of counted vmcnt dies. Rule #18: pair with explicit lgkmcnt(0) +
// sched_barrier(0) before the consuming MFMAs.
template <int IMM>
DEVINL short8 ds128o(uint32_t base) {
  short8 r;
  asm volatile("ds_read_b128 %0, %1 offset:%2" : "=v"(r) : "v"(base), "n"(IMM));
  return r;
}

#define MFMA16(a, b, c) __builtin_amdgcn_mfma_f32_16x16x32_bf16((a), (b), (c), 0, 0, 0)

// 0.125 (1/sqrt(Dk)) * log2(e): folds attention scale AND base-2 softmax into Q
#define QSCALE2 0.18033688011112042f

// ---------------------------------------------------------------------------
// prep: blocks 0..4095 cast x->bf16; 4096..8191 four 1024^2 transposes;
// 8192..12287 w1; 12288..16383 w2; 16384 converts mask(int)->bf16 0/1.
__global__ __launch_bounds__(256) void prep_kernel(
    const float* __restrict__ x, unsigned short* __restrict__ XB,
    const float* __restrict__ wq, const float* __restrict__ wk,
    const float* __restrict__ wv, const float* __restrict__ wo,
    unsigned short* __restrict__ WQKV, unsigned short* __restrict__ WOT,
    const float* __restrict__ w1, unsigned short* __restrict__ W1T,
    const float* __restrict__ w2, unsigned short* __restrict__ W2T,
    const int* __restrict__ mask, unsigned short* __restrict__ MB) {
  const int bid = blockIdx.x;
  if (bid >= 16384) {  // mask -> bf16 0/1
    const int i0 = threadIdx.x * 16;
#pragma unroll
    for (int j = 0; j < 16; ++j) MB[i0 + j] = mask[i0 + j] ? 0x3F80 : 0;
    return;
  }
  if (bid < 4096) {  // cast x (pair-packed hw cvt)
    const int i = (bid * 256 + threadIdx.x) * 4;
    floatx4 v = *(const floatx4*)(x + i);
    union { uint32_t u[2]; ushort4v v4; } o;
    o.u[0] = pkbf(v[0], v[1]);
    o.u[1] = pkbf(v[2], v[3]);
    *(ushort4v*)(XB + i) = o.v4;
    return;
  }
  const float* in;
  unsigned short* out;
  int K, N, bx, by;
  if (bid < 8192) {
    const int b2 = bid - 4096, z = b2 >> 10;
    in = (z == 0) ? wq : (z == 1) ? wk : (z == 2) ? wv : wo;
    out = (z == 3) ? WOT : WQKV + (size_t)z * 1024 * 1024;
    K = 1024; N = 1024; bx = b2 & 31; by = (b2 >> 5) & 31;
  } else if (bid < 12288) {
    const int b3 = bid - 8192;
    in = w1; out = W1T; K = 1024; N = 4096; bx = b3 & 127; by = b3 >> 7;
  } else {
    const int b4 = bid - 12288;
    in = w2; out = W2T; K = 4096; N = 1024; bx = b4 & 31; by = b4 >> 5;
  }
  __shared__ float tile[32][33];
  const int n0 = bx * 32, k0 = by * 32;
  const int tx = threadIdx.x & 31, ty = threadIdx.x >> 5;  // 32 x 8
#pragma unroll
  for (int i = 0; i < 4; ++i)
    tile[ty + 8 * i][tx] = in[(size_t)(k0 + ty + 8 * i) * N + n0 + tx];
  __syncthreads();
#pragma unroll
  for (int i = 0; i < 4; ++i)
    out[(size_t)(n0 + ty + 8 * i) * K + k0 + tx] = f2bf(tile[tx][ty + 8 * i]);
}

// ---------------------------------------------------------------------------
// Legacy 128^2 GEMM (kept for the small WO projection only).
template <int EPI, int SK>
__global__ __launch_bounds__(256, 3) void gemm_bt_kernel(
    const unsigned short* __restrict__ A, const unsigned short* __restrict__ BT,
    const float* __restrict__ bias, void* __restrict__ C0, void* __restrict__ C1,
    void* __restrict__ C2, int M, int N, int K, const int* __restrict__ msk) {
  __shared__ __align__(16) unsigned short As[128 * 64];   // 2 panels x 8KB
  __shared__ __align__(16) unsigned short Bs[128 * 64];
  const int tid = threadIdx.x;
  const int w = tid >> 6, l = tid & 63;
  const int lq = l >> 4, lr = l & 15;

  int bxs, bys;
  {  // 2x4 XCD rectangle swizzle (perf-only; any mapping is correct)
    const int nx = gridDim.x, ny = gridDim.y;
    const int f = blockIdx.y * nx + blockIdx.x;
    const int xcd = f & 7, s = f >> 3;
    const int q = nx >> 1, p = ny >> 2;     // rect = q cols x p rows
    bxs = (xcd & 1) * q + (s % q);
    bys = (xcd >> 1) * p + (s / q);
  }
  const int m0 = bys * 128, n0 = bxs * 128;
  const int wm = (w >> 1) * 64, wn = (w & 1) * 64;
  const int r_a = l >> 2;            // row within 16-row chunk
  const int colb = (l & 3) * 8;      // col (8 bf16 = 16B)
  const int kslice = K / SK;
  const int kbeg = kslice * blockIdx.z;

  floatx4 acc[4][4];
  const floatx4 fz = {0.f, 0.f, 0.f, 0.f};
#pragma unroll
  for (int mt = 0; mt < 4; ++mt)
#pragma unroll
    for (int nt = 0; nt < 4; ++nt) acc[mt][nt] = fz;

  for (int k0 = kbeg; k0 < kbeg + kslice; k0 += 64) {
    __syncthreads();
#pragma unroll
    for (int p = 0; p < 2; ++p) {
#pragma unroll
      for (int i = 0; i < 2; ++i) {
        const int c = w * 2 + i;
        load_lds_128(A + (size_t)(m0 + c * 16 + r_a) * K + k0 + p * 32 + colb,
                     (char*)As + p * 8192 + c * 1024);
        load_lds_128(BT + (size_t)(n0 + c * 16 + r_a) * K + k0 + p * 32 + colb,
                     (char*)Bs + p * 8192 + c * 1024);
      }
    }
    __syncthreads();
#pragma unroll
    for (int p = 0; p < 2; ++p) {
      short8 af[4], bf[4];
#pragma unroll
      for (int mt = 0; mt < 4; ++mt)
        af[mt] = *(const short8*)((const char*)As + p * 8192 + (wm + mt * 16 + lr) * 64 + lq * 16);
#pragma unroll
      for (int nt = 0; nt < 4; ++nt)
        bf[nt] = *(const short8*)((const char*)Bs + p * 8192 + (wn + nt * 16 + lr) * 64 + lq * 16);
#pragma unroll
      for (int mt = 0; mt < 4; ++mt)
#pragma unroll
        for (int nt = 0; nt < 4; ++nt)
          acc[mt][nt] = MFMA16(af[mt], bf[nt], acc[mt][nt]);
    }
  }

  void* Cp = (SK > 1 && blockIdx.z) ? C1 : C0;
#pragma unroll
  for (int mt = 0; mt < 4; ++mt) {
#pragma unroll
    for (int nt = 0; nt < 4; ++nt) {
      const int n = n0 + wn + nt * 16 + lr;
      float bval = 0.f;
      if (EPI == 2) bval = bias[n];
#pragma unroll
      for (int r = 0; r < 4; ++r) {
        const int m = m0 + wm + mt * 16 + lq * 4 + r;
        float v = acc[mt][nt][r];
        if (EPI == 4) {
          ((unsigned short*)Cp)[(size_t)m * N + n] = f2bf(v);
        } else if (EPI == 2) {
          ((unsigned short*)C0)[(size_t)m * N + n] = f2bf(fast_gelu(v + bval));
        }
      }
    }
  }
  (void)msk; (void)C2; (void)M;
}

// ---------------------------------------------------------------------------
// 256^2 8-phase GEMM, R2: in-loop LDS reads are inline-asm ds_read_b128
// (opaque to waitcnt legalizer) + per-phase {s_barrier; lgkmcnt(0);
// sched_barrier(0); setprio(1); 16 MFMA; setprio(0); s_barrier}. Counted
// vmcnt(8) once per K-tile (vmcnt(0) at the t==NT-2 boundary: tail fix).
// LDS 128KB: 2 buffers x {A[256][64], B[256][64]} bf16, XOR-swizzled
// (byte ^= (row&7)<<4): linear global_load_lds dest + inverse-swizzled
// global source + swizzled ds_read addrs (both-sides-or-neither).
// Liveness: A-X last read ph0; B-X ph0 (regs to ph3); B-Y ph1; A-Y ph2.
// Each stage issue is >=1 closing barrier after its region's last reader;
// within-phase {reads, stages} touch disjoint regions.
// EPI: 2 = bias + fast GELU -> bf16; 4 = bf16 partial (split-K z -> C0..C3);
//      5 = fused QKV epilogue (Q*QSCALE2 / K / V masked+permuted-transposed).
template <int EPI, int SK>
__global__ __launch_bounds__(512, 2) void gemm8_kernel(
    const unsigned short* __restrict__ A, const unsigned short* __restrict__ BT,
    const float* __restrict__ bias, void* __restrict__ C0, void* __restrict__ C1,
    void* __restrict__ C2, void* __restrict__ C3, int M, int N, int K,
    const int* __restrict__ msk) {
  __shared__ __align__(16) char smem[131072];
  const int tid = threadIdx.x;
  const int w = tid >> 6, l = tid & 63;
  const int lq = l >> 4, lr = l & 15;
  const int wr = w >> 2, wc = w & 3;

  int bxs, bys;
  {  // 2x4 XCD rectangle swizzle
    const int nx = gridDim.x, ny = gridDim.y;
    const int f = blockIdx.y * nx + blockIdx.x;
    const int xcd = f & 7, s = f >> 3;
    const int q = nx >> 1, p = ny >> 2;
    bxs = (xcd & 1) * q + (s % q);
    bys = (xcd >> 1) * p + (s / q);
  }
  const int m0 = bys * 256, n0 = bxs * 256;
  const int kslice = K / SK;
  const int kbeg = kslice * blockIdx.z;
  const int NT = kslice >> 6;                       // K-tiles of 64
  const int region = (EPI == 5) ? (n0 >> 10) : 0;   // block-uniform

  uint32_t mbits = 0xFFFFFFFFu;  // V-row mask, 32 packed bits (mt*4+r)
  if (EPI == 5 && region == 2) {
    mbits = 0;
#pragma unroll
    for (int mt = 0; mt < 8; ++mt) {
      const int4 m4 = *(const int4*)(msk + m0 + wr * 128 + mt * 16 + lq * 4);
      mbits |= (m4.x ? 1u : 0u) << (mt * 4);
      mbits |= (m4.y ? 1u : 0u) << (mt * 4 + 1);
      mbits |= (m4.z ? 1u : 0u) << (mt * 4 + 2);
      mbits |= (m4.w ? 1u : 0u) << (mt * 4 + 3);
    }
  }

  const int awb = w << 10;                            // A wave base (8KB piece)
  const int bwb = ((w >> 2) << 13) | ((w & 3) << 10); // B wave base (4KB pieces)

  // stage 1KB/wave: linear LDS dest (wave-uniform base; HW adds lane*16),
  // inverse-swizzled per-lane global source (m173 pattern).
  auto stage = [&](const unsigned short* __restrict__ G, int row0, int k,
                   int toff, int wb) {
    const int a = wb + (l << 4);
    const int r = a >> 7;
    const int cb = (a & 127) ^ ((r & 7) << 4);
    load_lds_128(G + (size_t)(row0 + r) * K + k + (cb >> 1), smem + toff + wb);
  };
  // half-tile stagers: 2 x global_load_lds (16KB) each
  auto stgAX = [&](int co, int k) { stage(A, m0, k, co, awb); stage(A, m0, k, co, 16384 + awb); };
  auto stgAY = [&](int co, int k) { stage(A, m0, k, co, 8192 + awb); stage(A, m0, k, co, 24576 + awb); };
  auto stgBX = [&](int co, int k) { stage(BT, n0, k, co + 32768, bwb); stage(BT, n0, k, co + 32768, 16384 + bwb); };
  auto stgBY = [&](int co, int k) { stage(BT, n0, k, co + 32768, 4096 + bwb); stage(BT, n0, k, co + 32768, 20480 + bwb); };

  floatx4 acc[8][4];
  const floatx4 fz = {0.f, 0.f, 0.f, 0.f};
#pragma unroll
  for (int mt = 0; mt < 8; ++mt)
#pragma unroll
    for (int nt = 0; nt < 4; ++nt) acc[mt][nt] = fz;

  // prologue: tiles 0,1 fully staged (16 loads/thread); drain to 8 = tile0 in
  stgAX(0, kbeg); stgAY(0, kbeg); stgBX(0, kbeg); stgBY(0, kbeg);
  stgAX(65536, kbeg + 64); stgAY(65536, kbeg + 64);
  stgBX(65536, kbeg + 64); stgBY(65536, kbeg + 64);
  asm volatile("s_waitcnt vmcnt(8)");
  __builtin_amdgcn_s_barrier();

  const uint32_t ldsb = (uint32_t)(uintptr_t)(lds_ptr_t)smem;  // LDS byte base
  const int arow = wr * 16384 + lr * 128;   // A frag row base (bytes in tile)
  const int brow = wc * 8192 + lr * 128;    // B frag row base
  const int xr = (lr & 7) << 4;             // read-side swizzle
  const int cb0 = (lq * 16) ^ xr;           // kk=0 col bytes
  const int cb1 = (64 + lq * 16) ^ xr;      // kk=1 col bytes

  for (int t = 0; t < NT; ++t) {
    const uint32_t co = (uint32_t)((t & 1) << 16);  // tile t and t+2 parity
    const uint32_t ab0 = ldsb + co + arow + cb0, ab1 = ldsb + co + arow + cb1;
    const uint32_t bb0 = ldsb + co + 32768 + brow + cb0;
    const uint32_t bb1 = ldsb + co + 32768 + brow + cb1;
    const int kpre = kbeg + (t + 2) * 64;
    const bool pre = (t + 2) < NT;
    short8 a0[4], a1[4], bX0[2], bX1[2], bY0[2], bY1[2];

    // ---- ph0: read A-X (rows wr*128+0..63) + B-X; MFMA quadrant (mt0-3, nt0-1)
    a0[0] = ds128o<0>(ab0);    a1[0] = ds128o<0>(ab1);
    a0[1] = ds128o<2048>(ab0); a1[1] = ds128o<2048>(ab1);
    a0[2] = ds128o<4096>(ab0); a1[2] = ds128o<4096>(ab1);
    a0[3] = ds128o<6144>(ab0); a1[3] = ds128o<6144>(ab1);
    bX0[0] = ds128o<0>(bb0);    bX1[0] = ds128o<0>(bb1);
    bX0[1] = ds128o<2048>(bb0); bX1[1] = ds128o<2048>(bb1);
    __builtin_amdgcn_s_barrier();
    asm volatile("s_waitcnt lgkmcnt(0)");
    __builtin_amdgcn_sched_barrier(0);
    __builtin_amdgcn_s_setprio(1);
#pragma unroll
    for (int mt = 0; mt < 4; ++mt)
#pragma unroll
      for (int nt = 0; nt < 2; ++nt) {
        acc[mt][nt] = MFMA16(a0[mt], bX0[nt], acc[mt][nt]);
        acc[mt][nt] = MFMA16(a1[mt], bX1[nt], acc[mt][nt]);
      }
    __builtin_amdgcn_s_setprio(0);
    __builtin_amdgcn_s_barrier();

    // ---- ph1: read B-Y; stage A-X,B-X of t+2; MFMA (mt0-3, nt2-3)
    bY0[0] = ds128o<4096>(bb0); bY1[0] = ds128o<4096>(bb1);
    bY0[1] = ds128o<6144>(bb0); bY1[1] = ds128o<6144>(bb1);
    if (pre) { stgAX(co, kpre); stgBX(co, kpre); }
    __builtin_amdgcn_s_barrier();
    asm volatile("s_waitcnt lgkmcnt(0)");
    __builtin_amdgcn_sched_barrier(0);
    __builtin_amdgcn_s_setprio(1);
#pragma unroll
    for (int mt = 0; mt < 4; ++mt)
#pragma unroll
      for (int nt = 0; nt < 2; ++nt) {
        acc[mt][2 + nt] = MFMA16(a0[mt], bY0[nt], acc[mt][2 + nt]);
        acc[mt][2 + nt] = MFMA16(a1[mt], bY1[nt], acc[mt][2 + nt]);
      }
    __builtin_amdgcn_s_setprio(0);
    __builtin_amdgcn_s_barrier();

    // ---- ph2: read A-Y (rows wr*128+64..127); stage B-Y of t+2; MFMA (mt4-7, nt2-3)
    a0[0] = ds128o<8192>(ab0);  a1[0] = ds128o<8192>(ab1);
    a0[1] = ds128o<10240>(ab0); a1[1] = ds128o<10240>(ab1);
    a0[2] = ds128o<12288>(ab0); a1[2] = ds128o<12288>(ab1);
    a0[3] = ds128o<14336>(ab0); a1[3] = ds128o<14336>(ab1);
    if (pre) stgBY(co, kpre);
    __builtin_amdgcn_s_barrier();
    asm volatile("s_waitcnt lgkmcnt(0)");
    __builtin_amdgcn_sched_barrier(0);
    __builtin_amdgcn_s_setprio(1);
#pragma unroll
    for (int mt = 0; mt < 4; ++mt)
#pragma unroll
      for (int nt = 0; nt < 2; ++nt) {
        acc[4 + mt][2 + nt] = MFMA16(a0[mt], bY0[nt], acc[4 + mt][2 + nt]);
        acc[4 + mt][2 + nt] = MFMA16(a1[mt], bY1[nt], acc[4 + mt][2 + nt]);
      }
    __builtin_amdgcn_s_setprio(0);
    __builtin_amdgcn_s_barrier();

    // ---- ph3: no reads (A-Y + B-X in regs); stage A-Y of t+2; MFMA (mt4-7, nt0-1)
    if (pre) stgAY(co, kpre);
    __builtin_amdgcn_s_barrier();
    __builtin_amdgcn_s_setprio(1);
#pragma unroll
    for (int mt = 0; mt < 4; ++mt)
#pragma unroll
      for (int nt = 0; nt < 2; ++nt) {
        acc[4 + mt][nt] = MFMA16(a0[mt], bX0[nt], acc[4 + mt][nt]);
        acc[4 + mt][nt] = MFMA16(a1[mt], bX1[nt], acc[4 + mt][nt]);
      }
    __builtin_amdgcn_s_setprio(0);
    // counted drain: tile t+1 landed, tile t+2's 8 loads stay in flight.
    // Tail fix: at t==NT-2 nothing new was issued -> must drain fully for
    // tile NT-1 (vmcnt(8) would be a no-op race).
    if (pre) asm volatile("s_waitcnt vmcnt(8)");
    else     asm volatile("s_waitcnt vmcnt(0)");
    __builtin_amdgcn_s_barrier();
  }

  // epilogue: m = m0 + wr*128 + mt*16 + lq*4 + r; n = n0 + wc*64 + nt*16 + lr
  void* Cp = C0;
  if (EPI == 4 && SK > 1) {
    const int z = blockIdx.z;
    Cp = (z == 0) ? C0 : (z == 1) ? C1 : (z == 2) ? C2 : C3;
  }
#pragma unroll
  for (int mt = 0; mt < 8; ++mt) {
#pragma unroll
    for (int nt = 0; nt < 4; ++nt) {
      const int n = n0 + wc * 64 + nt * 16 + lr;
      float bval = 0.f;
      if (EPI == 2) bval = bias[n];
#pragma unroll
      for (int r = 0; r < 4; ++r) {
        const int m = m0 + wr * 128 + mt * 16 + lq * 4 + r;
        float v = acc[mt][nt][r];
        if (EPI == 4) {
          ((unsigned short*)Cp)[(size_t)m * N + n] = f2bf(v);
        } else if (EPI == 2) {
          ((unsigned short*)C0)[(size_t)m * N + n] = f2bf(fast_gelu(v + bval));
        } else {  // EPI == 5
          if (region == 0) {
            ((unsigned short*)C0)[(size_t)m * 1024 + n] = f2bf(v * QSCALE2);
          } else if (region == 1) {
            ((unsigned short*)C1)[(size_t)m * 1024 + (n - 1024)] = f2bf(v);
          } else {
            const int nn = n - 2048;
            const int bidx = m >> 11, s = m & 2047;
            // key permutation within 32-group (flash phi order)
            const int u = s & 31;
            const int sp = (s & ~31) | (u & 3) | (((u >> 4) & 1) << 2) | (((u >> 2) & 3) << 3);
            const int hh = nn >> 6, d = nn & 63;
            const float vv = ((mbits >> (mt * 4 + r)) & 1u) ? v : 0.f;
            ((unsigned short*)C2)[((size_t)((bidx * 16 + hh) * 64 + d)) * 2048 + sp] = f2bf(vv);
          }
        }
      }
    }
  }
  (void)M;
}

// ---------------------------------------------------------------------------
// Flash attention: S=2048, Dk=64. Q PRE-SCALED by 0.125*log2e (exp2 domain).
__global__ __launch_bounds__(256, 2) void flash_kernel(
    const unsigned short* __restrict__ Q, const unsigned short* __restrict__ Kg,
    const unsigned short* __restrict__ VT, const unsigned short* __restrict__ MB,
    unsigned short* __restrict__ ctx) {
  __shared__ __align__(16) unsigned short Ks[128 * 64];    // [key][d] / Q stage, swizzled
  __shared__ __align__(16) unsigned short VTs[64 * 128];   // [d][key'], swizzled

  const int tid = threadIdx.x, w = tid >> 6, l = tid & 63;
  const int lq = l >> 4, lr = l & 15;
  const int lin = blockIdx.x;
  const int xcd = lin & 7, slot = lin >> 3;     // 64 slots per XCD
  const int bh = xcd * 4 + (slot >> 4);         // 4 heads per XCD
  const int b = bh >> 4, h = bh & 15;
  const int q0 = (slot & 15) * 128;

  const unsigned short* Qp = Q + (size_t)(b * 2048 + q0) * 1024 + h * 64;
  const unsigned short* Kp = Kg + (size_t)(b * 2048) * 1024 + h * 64;
  const unsigned short* VTp = VT + (size_t)bh * 64 * 2048;
  const unsigned short* mbp = MB + b * 2048;

  {  // stage Q [128][64] once through Ks (16KB: 16 chunks, 4 per wave)
    const int rq = l >> 3, cs = l & 7;
#pragma unroll
    for (int i = 0; i < 4; ++i) {
      const int c = w * 4 + i;
      load_lds_128(Qp + (size_t)(c * 8 + rq) * 1024 + cs * 8, (char*)Ks + c * 1024);
    }
  }
  __syncthreads();
  short8 qf[2][2];  // [qg][kstep]; lane holds Q[q0+w*32+qg*16+lr][d=lq*8+..]
#pragma unroll
  for (int qg = 0; qg < 2; ++qg) {
    qf[qg][0] = *(const short8*)((const char*)Ks + (w * 32 + qg * 16 + lr) * 128 + lq * 16);
    qf[qg][1] = *(const short8*)((const char*)Ks + (w * 32 + qg * 16 + lr) * 128 + 64 + lq * 16);
  }
  __syncthreads();  // Q consumed; Ks reused for K tiles

  const floatx4 fz = {0.f, 0.f, 0.f, 0.f};
  floatx4 o[2][4];
#pragma unroll
  for (int qg = 0; qg < 2; ++qg)
#pragma unroll
    for (int nt = 0; nt < 4; ++nt) o[qg][nt] = fz;
  floatx4 l_acc[2] = {fz, fz};

  const int krow = l >> 3, kslot = l & 7;   // Ks staging: 8 rows / 1KB chunk
  const int vrow = l >> 4, vslot = l & 15;  // VTs staging: 4 rows / 1KB chunk

  for (int kb = 0; kb < 2048; kb += 128) {
    if (kb) __syncthreads();
#pragma unroll
    for (int i = 0; i < 4; ++i) {
      const int c4 = w * 4 + i;
      {  // Ks rows c4*8..+7; slot kslot holds logical chunk kslot^(row&7)
        const int row = c4 * 8 + krow;
        const int cc = kslot ^ (row & 7);
        load_lds_128(Kp + (size_t)(kb + row) * 1024 + cc * 8, (char*)Ks + c4 * 1024);
      }
      {  // VTs rows c4*4..+3; slot vslot holds logical chunk vslot^(row&15)
        const int row = c4 * 4 + vrow;
        const int cc = vslot ^ (row & 15);
        load_lds_128(VTp + (size_t)row * 2048 + kb + cc * 8, (char*)VTs + c4 * 1024);
      }
    }
    // mask fragments for the 4 PV windows (already in phi key order)
    short8 mf[4];
#pragma unroll
    for (int t = 0; t < 4; ++t) {
      const short4v ma = *(const short4v*)(mbp + kb + t * 32 + lq * 4);
      const short4v mb2 = *(const short4v*)(mbp + kb + t * 32 + 16 + lq * 4);
      mf[t] = short8{ma[0], ma[1], ma[2], ma[3], mb2[0], mb2[1], mb2[2], mb2[3]};
    }
    __syncthreads();

    // two halves of 64 keys each: 4 score-groups -> 2 PV windows
#pragma unroll
    for (int h2 = 0; h2 < 2; ++h2) {
      // S^T for both q-groups; K fragment reads SHARED across qg
      floatx4 s[2][4];
#pragma unroll
      for (int gg = 0; gg < 4; ++gg) {
        const int g = h2 * 4 + gg;
        const char* rowp = (const char*)Ks + (g * 16 + lr) * 128;
        short8 k0 = *(const short8*)(rowp + ((lq) ^ (lr & 7)) * 16);
        short8 k1 = *(const short8*)(rowp + ((4 + lq) ^ (lr & 7)) * 16);
#pragma unroll
        for (int qg = 0; qg < 2; ++qg) {
          floatx4 t = MFMA16(k0, qf[qg][0], fz);
          s[qg][gg] = MFMA16(k1, qf[qg][1], t);
        }
      }
      // p = exp2(score), hw-packed to bf16 A-fragments (phi key order)
      short8 pf[2][2];  // [qg][tt]
#pragma unroll
      for (int qg = 0; qg < 2; ++qg)
#pragma unroll
        for (int tt = 0; tt < 2; ++tt) {
          const floatx4 sL = s[qg][tt * 2], sH = s[qg][tt * 2 + 1];
          union { uint32_t u[4]; short8 s8; } pk;
          pk.u[0] = pkbf(EXP2(sL[0]), EXP2(sL[1]));
          pk.u[1] = pkbf(EXP2(sL[2]), EXP2(sL[3]));
          pk.u[2] = pkbf(EXP2(sH[0]), EXP2(sH[1]));
          pk.u[3] = pkbf(EXP2(sH[2]), EXP2(sH[3]));
          pf[qg][tt] = pk.s8;
        }
      // PV: windows t = h2*2 + tt; V fragment reads SHARED across qg
#pragma unroll
      for (int tt = 0; tt < 2; ++tt) {
        const int t = h2 * 2 + tt;
        l_acc[0] = MFMA16(pf[0][tt], mf[t], l_acc[0]);
        l_acc[1] = MFMA16(pf[1][tt], mf[t], l_acc[1]);
#pragma unroll
        for (int nt = 0; nt < 4; ++nt) {
          const int d = nt * 16 + lr;
          short8 vf = *(const short8*)((const char*)VTs + d * 256 +
                                       (((t * 4 + lq) ^ (d & 15)) * 16));
          o[0][nt] = MFMA16(pf[0][tt], vf, o[0][nt]);
          o[1][nt] = MFMA16(pf[1][tt], vf, o[1][nt]);
        }
      }
    }
  }

  // epilogue: q = q0 + w*32 + qg*16 + lq*4 + r, d = nt*16 + lr
#pragma unroll
  for (int qg = 0; qg < 2; ++qg)
#pragma unroll
    for (int r = 0; r < 4; ++r) {
      const float inv = 1.0f / l_acc[qg][r];
      const int q = q0 + w * 32 + qg * 16 + lq * 4 + r;
#pragma unroll
      for (int nt = 0; nt < 4; ++nt)
        ctx[(size_t)(b * 2048 + q) * 1024 + h * 64 + nt * 16 + lr] = f2bf(o[qg][nt][r] * inv);
    }
}

// ---------------------------------------------------------------------------
// fused residual + NY bf16-partial sums + bias + LayerNorm over rows of 1024.
// v = res + y0 + y1 (+ y2 + y3) + bias; out = LN(v)*gamma + beta.
template <int RESBF, int OUTBF, int NY>
__global__ __launch_bounds__(256) void ln2_kernel(
    const void* __restrict__ res, const unsigned short* __restrict__ y0,
    const unsigned short* __restrict__ y1, const unsigned short* __restrict__ y2,
    const unsigned short* __restrict__ y3, const float* __restrict__ bias,
    const float* __restrict__ gamma, const float* __restrict__ beta,
    void* __restrict__ outp) {
  const int row = blockIdx.x, t = threadIdx.x;
  const size_t base = (size_t)row * 1024 + t * 4;
  float v[4];
  if (RESBF) {
    ushort4v r4 = *(const ushort4v*)((const unsigned short*)res + base);
#pragma unroll
    for (int j = 0; j < 4; ++j) v[j] = bf2f(r4[j]);
  } else {
    floatx4 r4 = *(const floatx4*)((const float*)res + base);
#pragma unroll
    for (int j = 0; j < 4; ++j) v[j] = r4[j];
  }
  const ushort4v a4 = *(const ushort4v*)(y0 + base);
  const ushort4v b4v = *(const ushort4v*)(y1 + base);
  ushort4v c4 = {0, 0, 0, 0}, d4 = {0, 0, 0, 0};
  if (NY == 4) {
    c4 = *(const ushort4v*)(y2 + base);
    d4 = *(const ushort4v*)(y3 + base);
  }
  const floatx4 bi4 = *(const floatx4*)(bias + t * 4);
  float s = 0.f, ss = 0.f;
#pragma unroll
  for (int j = 0; j < 4; ++j) {
    v[j] += bf2f(a4[j]) + bf2f(b4v[j]) + bi4[j];
    if (NY == 4) v[j] += bf2f(c4[j]) + bf2f(d4[j]);
    s += v[j];
    ss += v[j] * v[j];
  }
#pragma unroll
  for (int off = 1; off < 64; off <<= 1) {
    s += __shfl_xor(s, off);
    ss += __shfl_xor(ss, off);
  }
  __shared__ float red[8];
  const int w = t >> 6;
  if ((t & 63) == 0) { red[w] = s; red[4 + w] = ss; }
  __syncthreads();
  s = red[0] + red[1] + red[2] + red[3];
  ss = red[4] + red[5] + red[6] + red[7];
  const float mean = s * (1.0f / 1024.0f);
  const float var = ss * (1.0f / 1024.0f) - mean * mean;
  const float rstd = rsqrtf(var + 1e-6f);
  const floatx4 g4 = *(const floatx4*)(gamma + t * 4);
  const floatx4 be4 = *(const floatx4*)(beta + t * 4);
  if (OUTBF) {
    union { uint32_t u[2]; ushort4v v4; } o;
    o.u[0] = pkbf((v[0] - mean) * rstd * g4[0] + be4[0],
                  (v[1] - mean) * rstd * g4[1] + be4[1]);
    o.u[1] = pkbf((v[2] - mean) * rstd * g4[2] + be4[2],
                  (v[3] - mean) * rstd * g4[3] + be4[3]);
    *(ushort4v*)((unsigned short*)outp + base) = o.v4;
  } else {
    floatx4 o;
#pragma unroll
    for (int j = 0; j < 4; ++j) o[j] = (v[j] - mean) * rstd * g4[j] + be4[j];
    *(floatx4*)((float*)outp + base) = o;
  }
}

// ---------------------------------------------------------------------------
extern "C" void kernel_launch(void* const* d_in, const int* in_sizes, int n_in,
                              void* d_out, int out_size, void* d_ws, size_t ws_size,
                              hipStream_t stream) {
  (void)in_sizes; (void)n_in; (void)out_size; (void)ws_size;
  const float* x    = (const float*)d_in[0];
  const int*   mask = (const int*)d_in[1];
  const float* wq   = (const float*)d_in[2];
  const float* wk   = (const float*)d_in[3];
  const float* wv   = (const float*)d_in[4];
  const float* wo   = (const float*)d_in[5];
  const float* wo_b = (const float*)d_in[6];
  const float* w1   = (const float*)d_in[7];
  const float* b1   = (const float*)d_in[8];
  const float* w2   = (const float*)d_in[9];
  const float* b2   = (const float*)d_in[10];
  const float* g1   = (const float*)d_in[11];
  const float* be1  = (const float*)d_in[12];
  const float* g2   = (const float*)d_in[13];
  const float* be2  = (const float*)d_in[14];
  float* out = (float*)d_out;

  char* ws = (char*)d_ws;
  const size_t MBy = 1024ull * 1024ull;
  // phase-aliased workspace (80 MB):
  unsigned short* WQKV = (unsigned short*)(ws + 0 * MBy);   // 6MB  (dead after QKV gemm)
  unsigned short* WOT  = (unsigned short*)(ws + 6 * MBy);   // 2MB  (dead after WO gemm)
  unsigned short* W1T  = (unsigned short*)(ws + 8 * MBy);   // 8MB  (dead after FF1)
  unsigned short* W2T  = (unsigned short*)(ws + 16 * MBy);  // 8MB  (dead after FF2)
  unsigned short* XB   = (unsigned short*)(ws + 24 * MBy);  // 8MB  (dead after QKV)
  unsigned short* Qb   = (unsigned short*)(ws + 32 * MBy);  // 8MB  (dead after flash)
  unsigned short* Kb   = (unsigned short*)(ws + 40 * MBy);  // 8MB  (dead after flash)
  unsigned short* VTb  = (unsigned short*)(ws + 48 * MBy);  // 8MB  (dead after flash)
  unsigned short* CTX  = (unsigned short*)(ws + 56 * MBy);  // 8MB  (dead after WO gemm)
  unsigned short* ATT0 = (unsigned short*)(ws + 32 * MBy);  // 8MB bf16, over Qb
  unsigned short* ATT1 = (unsigned short*)(ws + 40 * MBy);  // 8MB bf16, over Kb
  unsigned short* Hb   = (unsigned short*)(ws + 24 * MBy);  // 8MB  over XB
  unsigned short* G1   = (unsigned short*)(ws + 32 * MBy);  // 32MB over ATT0/ATT1/VTb/CTX
  // FF2 split-K=4 bf16 partials, all in regions dead by step 7:
  unsigned short* P0   = (unsigned short*)(ws + 0 * MBy);   // over WQKV+WOT
  unsigned short* P1   = (unsigned short*)(ws + 8 * MBy);   // over W1T
  unsigned short* P2   = (unsigned short*)(ws + 64 * MBy);  // 8MB
  unsigned short* P3   = (unsigned short*)(ws + 72 * MBy);  // 8MB
  unsigned short* MB   = (unsigned short*)(ws + 78 * MBy);  // 8KB bf16 mask (inside P3
                                                            // region; P3 written after flash)

  // 1. prep: cast x + all 6 weight transposes + bf16 mask in one launch
  prep_kernel<<<16385, 256, 0, stream>>>(x, XB, wq, wk, wv, wo, WQKV, WOT,
                                         w1, W1T, w2, W2T, mask, MB);
  // 2. fused QKV projection (8-phase 256^2): N=3072 -> 192 blocks;
  //    Q pre-scaled, V masked+permuted
  gemm8_kernel<5, 1><<<dim3(12, 16), 512, 0, stream>>>(
      XB, WQKV, nullptr, Qb, Kb, VTb, nullptr, 4096, 3072, 1024, mask);
  // 3. attention (512 blocks, q-tile 128, XCD head-grouped)
  flash_kernel<<<512, 256, 0, stream>>>(Qb, Kb, VTb, MB, CTX);
  // 4. output projection (small; legacy kernel), split-K=2 bf16 partials
  gemm_bt_kernel<4, 2><<<dim3(8, 32, 2), 256, 0, stream>>>(
      CTX, WOT, nullptr, ATT0, ATT1, nullptr, 4096, 1024, 1024, nullptr);
  // 5. LN1: h = LN(x + att0 + att1 + wo_b) -> bf16
  ln2_kernel<0, 1, 2><<<4096, 256, 0, stream>>>(x, ATT0, ATT1, nullptr, nullptr,
                                                wo_b, g1, be1, Hb);
  // 6. FF1 + bias + fast GELU -> bf16 (8-phase 256^2, 256 blocks)
  gemm8_kernel<2, 1><<<dim3(16, 16), 512, 0, stream>>>(
      Hb, W1T, b1, G1, nullptr, nullptr, nullptr, 4096, 4096, 1024, nullptr);
  // 7. FF2 (8-phase 256^2), split-K=4 bf16 partials -> 256 blocks
  gemm8_kernel<4, 4><<<dim3(4, 16, 4), 512, 0, stream>>>(
      G1, W2T, nullptr, P0, P1, P2, P3, 4096, 1024, 4096, nullptr);
  // 8. LN2: out = LN(h + p0 + p1 + p2 + p3 + b2) -> fp32
  ln2_kernel<1, 0, 4><<<4096, 256, 0, stream>>>(Hb, P0, P1, P2, P3, b2, g2, be2, out);
}

// Round 3
// 325.504 us; speedup vs baseline: 1.0471x; 1.0471x over previous
//
#include <hip/hip_runtime.h>
#include <cstdint>

#define DEVINL __device__ __forceinline__

typedef __attribute__((ext_vector_type(8))) short short8;       // 8 x bf16 (4 VGPRs)
typedef __attribute__((ext_vector_type(4))) short short4v;      // 4 x bf16 (2 VGPRs)
typedef __attribute__((ext_vector_type(4))) float floatx4;
typedef __attribute__((ext_vector_type(4))) unsigned short ushort4v;

// hardware packed cvt: D = {bf16(a), bf16(b)} (RNE) — use ONLY for true pair
// packs (scalar use regressed R7: asm blocks CSE, +20 VGPR in GEMM epilogue).
DEVINL uint32_t pkbf(float a, float b) {
  uint32_t d;
  asm("v_cvt_pk_bf16_f32 %0, %1, %2" : "=v"(d) : "v"(a), "v"(b));
  return d;
}
// software RNE fp32->bf16 for scalar stores (compiler-schedulable)
DEVINL unsigned short f2bf(float f) {
  union { float f; uint32_t u; } v; v.f = f;
  return (unsigned short)((v.u + 0x7fffu + ((v.u >> 16) & 1u)) >> 16);
}
DEVINL float bf2f(unsigned short h) {
  union { uint32_t u; float f; } v; v.u = ((uint32_t)h) << 16;
  return v.f;
}

#if defined(__has_builtin) && __has_builtin(__builtin_amdgcn_exp2f)
#define EXP2(x) __builtin_amdgcn_exp2f(x)
#else
#define EXP2(x) exp2f(x)
#endif

// fast GELU (tanh form, exp2-based): max |err| ~3e-4 vs exact erf GELU.
DEVINL float fast_gelu(float v) {
  const float z = -2.30220795f * v * (1.0f + 0.044715f * v * v);
  return v * __builtin_amdgcn_rcpf(1.0f + EXP2(z));
}

typedef __attribute__((address_space(3))) unsigned char* lds_ptr_t;
typedef const __attribute__((address_space(1))) unsigned char* gbl_ptr_t;
// async global->LDS, 16B per lane; LDS dest = wave-uniform base + lane*16
DEVINL void load_lds_128(const void* g, void* l) {
  __builtin_amdgcn_global_load_lds((gbl_ptr_t)g, (lds_ptr_t)l, 16, 0, 0);
}

#define MFMA16(a, b, c) __builtin_amdgcn_mfma_f32_16x16x32_bf16((a), (b), (c), 0, 0, 0)

// 0.125 (1/sqrt(Dk)) * log2(e): folds attention scale AND base-2 softmax into Q
#define QSCALE2 0.18033688011112042f

// ---------------------------------------------------------------------------
// SESSION NOTE (R1/R2): 8-phase 256^2 gemm8 port ran at 63 µs vs gemm_bt's
// 50 µs on the same NT=16 shapes (MfmaUtil 15% vs 19%), and the inline-asm
// ds_read + lgkmcnt fence fix changed NOTHING (alias-drain theory falsified).
// Reverted to the proven 2-phase 128^2 gemm_bt (3 blocks/CU, inter-block
// overlap hides the drains). This round's lever: prep transpose coalescing.
// ---------------------------------------------------------------------------
// prep (R3): blocks 0..4095 cast x->bf16 (vectorized, pair-packed cvt);
// 4096..5119 four 1024^2 transposes (64x64 tiles); 5120..6143 w1 (64x64);
// 6144..7167 w2 (64x64); 7168 converts mask(int)->bf16 0/1.
// 64x64 tile: fp32 reads 256B-contiguous per 16-lane group; bf16 writes
// 128B-contiguous per 8-lane group (short8); LDS [64][65] pad -> 2-way
// bank aliasing (free, m136) on both passes. Old 32x32 version wrote 64B
// rows (uncoalesced tax) with 4x the block count.
__global__ __launch_bounds__(256) void prep_kernel(
    const float* __restrict__ x, unsigned short* __restrict__ XB,
    const float* __restrict__ wq, const float* __restrict__ wk,
    const float* __restrict__ wv, const float* __restrict__ wo,
    unsigned short* __restrict__ WQKV, unsigned short* __restrict__ WOT,
    const float* __restrict__ w1, unsigned short* __restrict__ W1T,
    const float* __restrict__ w2, unsigned short* __restrict__ W2T,
    const int* __restrict__ mask, unsigned short* __restrict__ MB) {
  const int bid = blockIdx.x;
  const int t = threadIdx.x;
  if (bid >= 7168) {  // mask -> bf16 0/1
    const int i0 = t * 16;
#pragma unroll
    for (int j = 0; j < 16; ++j) MB[i0 + j] = mask[i0 + j] ? 0x3F80 : 0;
    return;
  }
  if (bid < 4096) {  // cast x (pair-packed hw cvt)
    const int i = (bid * 256 + t) * 4;
    floatx4 v = *(const floatx4*)(x + i);
    union { uint32_t u[2]; ushort4v v4; } o;
    o.u[0] = pkbf(v[0], v[1]);
    o.u[1] = pkbf(v[2], v[3]);
    *(ushort4v*)(XB + i) = o.v4;
    return;
  }
  // 64x64 transpose tiles
  const float* in;
  unsigned short* out;
  int K, N, bx, by;
  if (bid < 5120) {  // wq/wk/wv/wo (1024^2 each, 256 tiles each)
    const int b2 = bid - 4096, z = b2 >> 8, bb = b2 & 255;
    in = (z == 0) ? wq : (z == 1) ? wk : (z == 2) ? wv : wo;
    out = (z == 3) ? WOT : WQKV + (size_t)z * 1024 * 1024;
    K = 1024; N = 1024; bx = bb & 15; by = bb >> 4;
  } else if (bid < 6144) {  // w1 [1024][4096] -> W1T [4096][1024]
    const int b3 = bid - 5120;
    in = w1; out = W1T; K = 1024; N = 4096; bx = b3 & 63; by = b3 >> 6;
  } else {  // w2 [4096][1024] -> W2T [1024][4096]
    const int b4 = bid - 6144;
    in = w2; out = W2T; K = 4096; N = 1024; bx = b4 & 15; by = b4 >> 4;
  }
  __shared__ float tile[64][65];  // tile[k][n]; 65-pad -> bank = (k + n) % 32
  const int n0 = bx * 64, k0 = by * 64;
  const int rl = t >> 4, c4 = (t & 15) * 4;  // load: 16 rows/pass x 64 cols
#pragma unroll
  for (int p = 0; p < 4; ++p) {
    const int r = rl + 16 * p;
    const floatx4 v = *(const floatx4*)(in + (size_t)(k0 + r) * N + n0 + c4);
#pragma unroll
    for (int j = 0; j < 4; ++j) tile[r][c4 + j] = v[j];
  }
  __syncthreads();
  const int rw = t >> 3, c8 = (t & 7) * 8;   // write: 32 rows/pass x 64 cols
#pragma unroll
  for (int p = 0; p < 2; ++p) {
    const int row = rw + 32 * p;             // output n-row
    union { unsigned short h[8]; short8 s8; } o;
#pragma unroll
    for (int j = 0; j < 8; ++j) o.h[j] = f2bf(tile[c8 + j][row]);
    *(short8*)(out + (size_t)(n0 + row) * K + k0 + c8) = o.s8;
  }
}

// ---------------------------------------------------------------------------
// GEMM: C = A[M,K] @ BT[N,K]^T (bf16 in, fp32 acc), BM=BN=128, BK=64, 256 thr.
// 16x16x32 MFMA, 4x4 acc/wave; __launch_bounds__(256,3) -> 3 blocks/CU.
// XCD RECTANGLE SWIZZLE (R14): hardware assigns xcd = dispatch_id & 7; with
// nx % 8 == 0 the natural mapping gives each XCD one COLUMN STRIP (all of A
// streamed through its 4MB L2 — R13 showed FF2 FETCH 135MB vs 40MB
// footprint). Remap so the 8 XCDs tile the grid 2x4: each owns nx/2 cols x
// ny/4 rows -> per-XCD footprint ~5-6MB instead of 16+MB.
// LDS A/B each stored as TWO stacked 32-K panels of 64-B rows.
// SK: split-K (blockIdx.z; slice0->C0, slice1->C1).
// EPI: 2 = bias + fast GELU -> bf16
//      4 = bf16 partial store (split-K; bias added downstream in LN)
//      5 = fused QKV epilogue: region 0 -> Q*QSCALE2 (C0); 1 -> K (C1);
//          2 -> V * mask, per-head-transposed [bh][64][2048] with keys
//          permuted within 32-groups (flash phi order) (C2)
template <int EPI, int SK>
__global__ __launch_bounds__(256, 3) void gemm_bt_kernel(
    const unsigned short* __restrict__ A, const unsigned short* __restrict__ BT,
    const float* __restrict__ bias, void* __restrict__ C0, void* __restrict__ C1,
    void* __restrict__ C2, int M, int N, int K, const int* __restrict__ msk) {
  __shared__ __align__(16) unsigned short As[128 * 64];   // 2 panels x 8KB
  __shared__ __align__(16) unsigned short Bs[128 * 64];
  const int tid = threadIdx.x;
  const int w = tid >> 6, l = tid & 63;
  const int lq = l >> 4, lr = l & 15;

  int bxs, bys;
  {  // 2x4 XCD rectangle swizzle (perf-only; any mapping is correct)
    const int nx = gridDim.x, ny = gridDim.y;
    const int f = blockIdx.y * nx + blockIdx.x;
    const int xcd = f & 7, s = f >> 3;
    const int q = nx >> 1, p = ny >> 2;     // rect = q cols x p rows
    bxs = (xcd & 1) * q + (s % q);
    bys = (xcd >> 1) * p + (s / q);
  }
  const int m0 = bys * 128, n0 = bxs * 128;
  const int wm = (w >> 1) * 64, wn = (w & 1) * 64;
  const int r_a = l >> 2;            // row within 16-row chunk
  const int colb = (l & 3) * 8;      // col (8 bf16 = 16B)
  const int kslice = K / SK;
  const int kbeg = kslice * blockIdx.z;
  const int region = (EPI == 5) ? (n0 >> 10) : 0;  // block-uniform

  // V-row mask, 16 packed bits (loads overlap the K-loop staging)
  uint32_t mbits = 0xFFFFu;
  if (EPI == 5 && region == 2) {
    mbits = 0;
#pragma unroll
    for (int mt = 0; mt < 4; ++mt) {
      const int4 m4 = *(const int4*)(msk + m0 + wm + mt * 16 + lq * 4);
      mbits |= (m4.x ? 1u : 0u) << (mt * 4);
      mbits |= (m4.y ? 1u : 0u) << (mt * 4 + 1);
      mbits |= (m4.z ? 1u : 0u) << (mt * 4 + 2);
      mbits |= (m4.w ? 1u : 0u) << (mt * 4 + 3);
    }
  }

  floatx4 acc[4][4];
  const floatx4 fz = {0.f, 0.f, 0.f, 0.f};
#pragma unroll
  for (int mt = 0; mt < 4; ++mt)
#pragma unroll
    for (int nt = 0; nt < 4; ++nt) acc[mt][nt] = fz;

  for (int k0 = kbeg; k0 < kbeg + kslice; k0 += 64) {
    __syncthreads();
#pragma unroll
    for (int p = 0; p < 2; ++p) {
#pragma unroll
      for (int i = 0; i < 2; ++i) {
        const int c = w * 2 + i;
        load_lds_128(A + (size_t)(m0 + c * 16 + r_a) * K + k0 + p * 32 + colb,
                     (char*)As + p * 8192 + c * 1024);
        load_lds_128(BT + (size_t)(n0 + c * 16 + r_a) * K + k0 + p * 32 + colb,
                     (char*)Bs + p * 8192 + c * 1024);
      }
    }
    __syncthreads();
#pragma unroll
    for (int p = 0; p < 2; ++p) {
      short8 af[4], bf[4];
#pragma unroll
      for (int mt = 0; mt < 4; ++mt)
        af[mt] = *(const short8*)((const char*)As + p * 8192 + (wm + mt * 16 + lr) * 64 + lq * 16);
#pragma unroll
      for (int nt = 0; nt < 4; ++nt)
        bf[nt] = *(const short8*)((const char*)Bs + p * 8192 + (wn + nt * 16 + lr) * 64 + lq * 16);
#pragma unroll
      for (int mt = 0; mt < 4; ++mt)
#pragma unroll
        for (int nt = 0; nt < 4; ++nt)
          acc[mt][nt] = MFMA16(af[mt], bf[nt], acc[mt][nt]);
    }
  }

  void* Cp = (SK > 1 && blockIdx.z) ? C1 : C0;
  // epilogue: C row = quad*4+reg, col = lane&15
#pragma unroll
  for (int mt = 0; mt < 4; ++mt) {
#pragma unroll
    for (int nt = 0; nt < 4; ++nt) {
      const int n = n0 + wn + nt * 16 + lr;
      float bval = 0.f;
      if (EPI == 2) bval = bias[n];
#pragma unroll
      for (int r = 0; r < 4; ++r) {
        const int m = m0 + wm + mt * 16 + lq * 4 + r;
        float v = acc[mt][nt][r];
        if (EPI == 4) {
          ((unsigned short*)Cp)[(size_t)m * N + n] = f2bf(v);
        } else if (EPI == 2) {
          ((unsigned short*)C0)[(size_t)m * N + n] = f2bf(fast_gelu(v + bval));
        } else {  // EPI == 5
          if (region == 0) {
            ((unsigned short*)C0)[(size_t)m * 1024 + n] = f2bf(v * QSCALE2);
          } else if (region == 1) {
            ((unsigned short*)C1)[(size_t)m * 1024 + (n - 1024)] = f2bf(v);
          } else {
            const int nn = n - 2048;
            const int bidx = m >> 11, s = m & 2047;
            // key permutation within 32-group: p = (u&3)|(bit4<<2)|((u>>2&3)<<3)
            const int u = s & 31;
            const int sp = (s & ~31) | (u & 3) | (((u >> 4) & 1) << 2) | (((u >> 2) & 3) << 3);
            const int hh = nn >> 6, d = nn & 63;
            const float vv = ((mbits >> (mt * 4 + r)) & 1u) ? v : 0.f;
            ((unsigned short*)C2)[((size_t)((bidx * 16 + hh) * 64 + d)) * 2048 + sp] = f2bf(vv);
          }
        }
      }
    }
  }
}

// ---------------------------------------------------------------------------
// Flash attention: S=2048, Dk=64. Q PRE-SCALED by 0.125*log2e (exp2 domain).
// FIXED-SHIFT softmax + TRANSPOSED-SCORE register pipeline (S^T = K·Q^T;
// C/D fragment is directly the PV A-operand under phi; V pre-permuted so the
// V B-fragment is one ds_read_b128). Q-tile 128 rows/block: K/V fragment
// reads shared across two q-groups per wave (halves LDS read traffic).
// XCD head-grouping: xcd owns 4 heads. LDS 32 KB. 512 blocks.
__global__ __launch_bounds__(256, 2) void flash_kernel(
    const unsigned short* __restrict__ Q, const unsigned short* __restrict__ Kg,
    const unsigned short* __restrict__ VT, const unsigned short* __restrict__ MB,
    unsigned short* __restrict__ ctx) {
  __shared__ __align__(16) unsigned short Ks[128 * 64];    // [key][d] / Q stage, swizzled
  __shared__ __align__(16) unsigned short VTs[64 * 128];   // [d][key'], swizzled

  const int tid = threadIdx.x, w = tid >> 6, l = tid & 63;
  const int lq = l >> 4, lr = l & 15;
  const int lin = blockIdx.x;
  const int xcd = lin & 7, slot = lin >> 3;     // 64 slots per XCD
  const int bh = xcd * 4 + (slot >> 4);         // 4 heads per XCD
  const int b = bh >> 4, h = bh & 15;
  const int q0 = (slot & 15) * 128;

  const unsigned short* Qp = Q + (size_t)(b * 2048 + q0) * 1024 + h * 64;
  const unsigned short* Kp = Kg + (size_t)(b * 2048) * 1024 + h * 64;
  const unsigned short* VTp = VT + (size_t)bh * 64 * 2048;
  const unsigned short* mbp = MB + b * 2048;

  {  // stage Q [128][64] once through Ks (16KB: 16 chunks, 4 per wave)
    const int rq = l >> 3, cs = l & 7;
#pragma unroll
    for (int i = 0; i < 4; ++i) {
      const int c = w * 4 + i;
      load_lds_128(Qp + (size_t)(c * 8 + rq) * 1024 + cs * 8, (char*)Ks + c * 1024);
    }
  }
  __syncthreads();
  short8 qf[2][2];  // [qg][kstep]; lane holds Q[q0+w*32+qg*16+lr][d=lq*8+..]
#pragma unroll
  for (int qg = 0; qg < 2; ++qg) {
    qf[qg][0] = *(const short8*)((const char*)Ks + (w * 32 + qg * 16 + lr) * 128 + lq * 16);
    qf[qg][1] = *(const short8*)((const char*)Ks + (w * 32 + qg * 16 + lr) * 128 + 64 + lq * 16);
  }
  __syncthreads();  // Q consumed; Ks reused for K tiles

  const floatx4 fz = {0.f, 0.f, 0.f, 0.f};
  floatx4 o[2][4];
#pragma unroll
  for (int qg = 0; qg < 2; ++qg)
#pragma unroll
    for (int nt = 0; nt < 4; ++nt) o[qg][nt] = fz;
  floatx4 l_acc[2] = {fz, fz};

  const int krow = l >> 3, kslot = l & 7;   // Ks staging: 8 rows / 1KB chunk
  const int vrow = l >> 4, vslot = l & 15;  // VTs staging: 4 rows / 1KB chunk

  for (int kb = 0; kb < 2048; kb += 128) {
    if (kb) __syncthreads();
#pragma unroll
    for (int i = 0; i < 4; ++i) {
      const int c4 = w * 4 + i;
      {  // Ks rows c4*8..+7; slot kslot holds logical chunk kslot^(row&7)
        const int row = c4 * 8 + krow;
        const int cc = kslot ^ (row & 7);
        load_lds_128(Kp + (size_t)(kb + row) * 1024 + cc * 8, (char*)Ks + c4 * 1024);
      }
      {  // VTs rows c4*4..+3; slot vslot holds logical chunk vslot^(row&15)
        const int row = c4 * 4 + vrow;
        const int cc = vslot ^ (row & 15);
        load_lds_128(VTp + (size_t)row * 2048 + kb + cc * 8, (char*)VTs + c4 * 1024);
      }
    }
    // mask fragments for the 4 PV windows (already in phi key order)
    short8 mf[4];
#pragma unroll
    for (int t = 0; t < 4; ++t) {
      const short4v ma = *(const short4v*)(mbp + kb + t * 32 + lq * 4);
      const short4v mb2 = *(const short4v*)(mbp + kb + t * 32 + 16 + lq * 4);
      mf[t] = short8{ma[0], ma[1], ma[2], ma[3], mb2[0], mb2[1], mb2[2], mb2[3]};
    }
    __syncthreads();

    // two halves of 64 keys each: 4 score-groups -> 2 PV windows
#pragma unroll
    for (int h2 = 0; h2 < 2; ++h2) {
      // S^T for both q-groups; K fragment reads SHARED across qg
      floatx4 s[2][4];
#pragma unroll
      for (int gg = 0; gg < 4; ++gg) {
        const int g = h2 * 4 + gg;
        const char* rowp = (const char*)Ks + (g * 16 + lr) * 128;
        short8 k0 = *(const short8*)(rowp + ((lq) ^ (lr & 7)) * 16);
        short8 k1 = *(const short8*)(rowp + ((4 + lq) ^ (lr & 7)) * 16);
#pragma unroll
        for (int qg = 0; qg < 2; ++qg) {
          floatx4 t = MFMA16(k0, qf[qg][0], fz);
          s[qg][gg] = MFMA16(k1, qf[qg][1], t);
        }
      }
      // p = exp2(score), hw-packed to bf16 A-fragments (phi key order)
      short8 pf[2][2];  // [qg][tt]
#pragma unroll
      for (int qg = 0; qg < 2; ++qg)
#pragma unroll
        for (int tt = 0; tt < 2; ++tt) {
          const floatx4 sL = s[qg][tt * 2], sH = s[qg][tt * 2 + 1];
          union { uint32_t u[4]; short8 s8; } pk;
          pk.u[0] = pkbf(EXP2(sL[0]), EXP2(sL[1]));
          pk.u[1] = pkbf(EXP2(sL[2]), EXP2(sL[3]));
          pk.u[2] = pkbf(EXP2(sH[0]), EXP2(sH[1]));
          pk.u[3] = pkbf(EXP2(sH[2]), EXP2(sH[3]));
          pf[qg][tt] = pk.s8;
        }
      // PV: windows t = h2*2 + tt; V fragment reads SHARED across qg
#pragma unroll
      for (int tt = 0; tt < 2; ++tt) {
        const int t = h2 * 2 + tt;
        l_acc[0] = MFMA16(pf[0][tt], mf[t], l_acc[0]);
        l_acc[1] = MFMA16(pf[1][tt], mf[t], l_acc[1]);
#pragma unroll
        for (int nt = 0; nt < 4; ++nt) {
          const int d = nt * 16 + lr;
          short8 vf = *(const short8*)((const char*)VTs + d * 256 +
                                       (((t * 4 + lq) ^ (d & 15)) * 16));
          o[0][nt] = MFMA16(pf[0][tt], vf, o[0][nt]);
          o[1][nt] = MFMA16(pf[1][tt], vf, o[1][nt]);
        }
      }
    }
  }

  // epilogue: q = q0 + w*32 + qg*16 + lq*4 + r, d = nt*16 + lr
#pragma unroll
  for (int qg = 0; qg < 2; ++qg)
#pragma unroll
    for (int r = 0; r < 4; ++r) {
      const float inv = 1.0f / l_acc[qg][r];
      const int q = q0 + w * 32 + qg * 16 + lq * 4 + r;
#pragma unroll
      for (int nt = 0; nt < 4; ++nt)
        ctx[(size_t)(b * 2048 + q) * 1024 + h * 64 + nt * 16 + lr] = f2bf(o[qg][nt][r] * inv);
    }
}

// ---------------------------------------------------------------------------
// fused residual + dual bf16-partial sum + bias + LayerNorm over rows of 1024.
// v = res + y0 + y1 + bias; out = LN(v)*gamma + beta.
template <int RESBF, int OUTBF>
__global__ __launch_bounds__(256) void ln2_kernel(
    const void* __restrict__ res, const unsigned short* __restrict__ y0,
    const unsigned short* __restrict__ y1, const float* __restrict__ bias,
    const float* __restrict__ gamma, const float* __restrict__ beta,
    void* __restrict__ outp) {
  const int row = blockIdx.x, t = threadIdx.x;
  const size_t base = (size_t)row * 1024 + t * 4;
  float v[4];
  if (RESBF) {
    ushort4v r4 = *(const ushort4v*)((const unsigned short*)res + base);
#pragma unroll
    for (int j = 0; j < 4; ++j) v[j] = bf2f(r4[j]);
  } else {
    floatx4 r4 = *(const floatx4*)((const float*)res + base);
#pragma unroll
    for (int j = 0; j < 4; ++j) v[j] = r4[j];
  }
  const ushort4v a4 = *(const ushort4v*)(y0 + base);
  const ushort4v b4v = *(const ushort4v*)(y1 + base);
  const floatx4 bi4 = *(const floatx4*)(bias + t * 4);
  float s = 0.f, ss = 0.f;
#pragma unroll
  for (int j = 0; j < 4; ++j) {
    v[j] += bf2f(a4[j]) + bf2f(b4v[j]) + bi4[j];
    s += v[j];
    ss += v[j] * v[j];
  }
#pragma unroll
  for (int off = 1; off < 64; off <<= 1) {
    s += __shfl_xor(s, off);
    ss += __shfl_xor(ss, off);
  }
  __shared__ float red[8];
  const int w = t >> 6;
  if ((t & 63) == 0) { red[w] = s; red[4 + w] = ss; }
  __syncthreads();
  s = red[0] + red[1] + red[2] + red[3];
  ss = red[4] + red[5] + red[6] + red[7];
  const float mean = s * (1.0f / 1024.0f);
  const float var = ss * (1.0f / 1024.0f) - mean * mean;
  const float rstd = rsqrtf(var + 1e-6f);
  const floatx4 g4 = *(const floatx4*)(gamma + t * 4);
  const floatx4 be4 = *(const floatx4*)(beta + t * 4);
  if (OUTBF) {
    union { uint32_t u[2]; ushort4v v4; } o;
    o.u[0] = pkbf((v[0] - mean) * rstd * g4[0] + be4[0],
                  (v[1] - mean) * rstd * g4[1] + be4[1]);
    o.u[1] = pkbf((v[2] - mean) * rstd * g4[2] + be4[2],
                  (v[3] - mean) * rstd * g4[3] + be4[3]);
    *(ushort4v*)((unsigned short*)outp + base) = o.v4;
  } else {
    floatx4 o;
#pragma unroll
    for (int j = 0; j < 4; ++j) o[j] = (v[j] - mean) * rstd * g4[j] + be4[j];
    *(floatx4*)((float*)outp + base) = o;
  }
}

// ---------------------------------------------------------------------------
extern "C" void kernel_launch(void* const* d_in, const int* in_sizes, int n_in,
                              void* d_out, int out_size, void* d_ws, size_t ws_size,
                              hipStream_t stream) {
  (void)in_sizes; (void)n_in; (void)out_size; (void)ws_size;
  const float* x    = (const float*)d_in[0];
  const int*   mask = (const int*)d_in[1];
  const float* wq   = (const float*)d_in[2];
  const float* wk   = (const float*)d_in[3];
  const float* wv   = (const float*)d_in[4];
  const float* wo   = (const float*)d_in[5];
  const float* wo_b = (const float*)d_in[6];
  const float* w1   = (const float*)d_in[7];
  const float* b1   = (const float*)d_in[8];
  const float* w2   = (const float*)d_in[9];
  const float* b2   = (const float*)d_in[10];
  const float* g1   = (const float*)d_in[11];
  const float* be1  = (const float*)d_in[12];
  const float* g2   = (const float*)d_in[13];
  const float* be2  = (const float*)d_in[14];
  float* out = (float*)d_out;

  char* ws = (char*)d_ws;
  const size_t MBy = 1024ull * 1024ull;
  // phase-aliased workspace (80 MB):
  unsigned short* WQKV = (unsigned short*)(ws + 0 * MBy);   // 6MB  (dead after QKV gemm)
  unsigned short* WOT  = (unsigned short*)(ws + 6 * MBy);   // 2MB  (dead after WO gemm)
  unsigned short* W1T  = (unsigned short*)(ws + 8 * MBy);   // 8MB  (dead after FF1)
  unsigned short* W2T  = (unsigned short*)(ws + 16 * MBy);  // 8MB  (dead after FF2)
  unsigned short* XB   = (unsigned short*)(ws + 24 * MBy);  // 8MB  (dead after QKV)
  unsigned short* Qb   = (unsigned short*)(ws + 32 * MBy);  // 8MB  (dead after flash)
  unsigned short* Kb   = (unsigned short*)(ws + 40 * MBy);  // 8MB  (dead after flash)
  unsigned short* VTb  = (unsigned short*)(ws + 48 * MBy);  // 8MB  (dead after flash)
  unsigned short* CTX  = (unsigned short*)(ws + 56 * MBy);  // 8MB  (dead after WO gemm)
  unsigned short* ATT0 = (unsigned short*)(ws + 32 * MBy);  // 8MB bf16, over Qb
  unsigned short* ATT1 = (unsigned short*)(ws + 40 * MBy);  // 8MB bf16, over Kb
  unsigned short* Hb   = (unsigned short*)(ws + 24 * MBy);  // 8MB  over XB
  unsigned short* G1   = (unsigned short*)(ws + 32 * MBy);  // 32MB over ATT0/ATT1/VTb/CTX
  unsigned short* FF20 = (unsigned short*)(ws + 64 * MBy);  // 8MB bf16
  unsigned short* FF21 = (unsigned short*)(ws + 72 * MBy);  // 8MB bf16
  unsigned short* MB   = (unsigned short*)(ws + 78 * MBy);  // 8KB bf16 mask (inside FF21
                                                            // region; FF21 written after flash)

  // 1. prep: cast x + all 6 weight transposes (64x64 coalesced) + bf16 mask
  prep_kernel<<<7169, 256, 0, stream>>>(x, XB, wq, wk, wv, wo, WQKV, WOT,
                                        w1, W1T, w2, W2T, mask, MB);
  // 2. fused QKV projection: N=3072 -> 768 blocks; Q pre-scaled, V masked+permuted
  gemm_bt_kernel<5, 1><<<dim3(24, 32), 256, 0, stream>>>(
      XB, WQKV, nullptr, Qb, Kb, VTb, 4096, 3072, 1024, mask);
  // 3. attention (512 blocks, q-tile 128, XCD head-grouped)
  flash_kernel<<<512, 256, 0, stream>>>(Qb, Kb, VTb, MB, CTX);
  // 4. output projection, split-K=2 bf16 partials (bias folded into LN1)
  gemm_bt_kernel<4, 2><<<dim3(8, 32, 2), 256, 0, stream>>>(
      CTX, WOT, nullptr, ATT0, ATT1, nullptr, 4096, 1024, 1024, nullptr);
  // 5. LN1: h = LN(x + att0 + att1 + wo_b) -> bf16
  ln2_kernel<0, 1><<<4096, 256, 0, stream>>>(x, ATT0, ATT1, wo_b, g1, be1, Hb);
  // 6. FF1 + bias + fast GELU -> bf16
  gemm_bt_kernel<2, 1><<<dim3(32, 32), 256, 0, stream>>>(
      Hb, W1T, b1, G1, nullptr, nullptr, 4096, 4096, 1024, nullptr);
  // 7. FF2, split-K=2 bf16 partials (bias folded into LN2)
  gemm_bt_kernel<4, 2><<<dim3(8, 32, 2), 256, 0, stream>>>(
      G1, W2T, nullptr, FF20, FF21, nullptr, 4096, 1024, 4096, nullptr);
  // 8. LN2: out = LN(h + ff0 + ff1 + b2) -> fp32
  ln2_kernel<1, 0><<<4096, 256, 0, stream>>>(Hb, FF20, FF21, b2, g2, be2, out);
}

// Round 4
// 311.737 us; speedup vs baseline: 1.0934x; 1.0442x over previous
//
#include <hip/hip_runtime.h>
#include <cstdint>

#define DEVINL __device__ __forceinline__

typedef __attribute__((ext_vector_type(8))) short short8;       // 8 x bf16 (4 VGPRs)
typedef __attribute__((ext_vector_type(4))) short short4v;      // 4 x bf16 (2 VGPRs)
typedef __attribute__((ext_vector_type(4))) float floatx4;
typedef __attribute__((ext_vector_type(4))) unsigned short ushort4v;

// hardware packed cvt: D = {bf16(a), bf16(b)} (RNE) — use ONLY for true pair
// packs (scalar use regressed R7: asm blocks CSE, +20 VGPR in GEMM epilogue).
DEVINL uint32_t pkbf(float a, float b) {
  uint32_t d;
  asm("v_cvt_pk_bf16_f32 %0, %1, %2" : "=v"(d) : "v"(a), "v"(b));
  return d;
}
// software RNE fp32->bf16 for scalar stores (compiler-schedulable)
DEVINL unsigned short f2bf(float f) {
  union { float f; uint32_t u; } v; v.f = f;
  return (unsigned short)((v.u + 0x7fffu + ((v.u >> 16) & 1u)) >> 16);
}
DEVINL float bf2f(unsigned short h) {
  union { uint32_t u; float f; } v; v.u = ((uint32_t)h) << 16;
  return v.f;
}

#if defined(__has_builtin) && __has_builtin(__builtin_amdgcn_exp2f)
#define EXP2(x) __builtin_amdgcn_exp2f(x)
#else
#define EXP2(x) exp2f(x)
#endif

// fast GELU (tanh form, exp2-based): max |err| ~3e-4 vs exact erf GELU.
DEVINL float fast_gelu(float v) {
  const float z = -2.30220795f * v * (1.0f + 0.044715f * v * v);
  return v * __builtin_amdgcn_rcpf(1.0f + EXP2(z));
}

typedef __attribute__((address_space(3))) unsigned char* lds_ptr_t;
typedef const __attribute__((address_space(1))) unsigned char* gbl_ptr_t;
// async global->LDS, 16B per lane; LDS dest = wave-uniform base + lane*16
DEVINL void load_lds_128(const void* g, void* l) {
  __builtin_amdgcn_global_load_lds((gbl_ptr_t)g, (lds_ptr_t)l, 16, 0, 0);
}

#define MFMA16(a, b, c) __builtin_amdgcn_mfma_f32_16x16x32_bf16((a), (b), (c), 0, 0, 0)

// 0.125 (1/sqrt(Dk)) * log2(e): folds attention scale AND base-2 softmax into Q
#define QSCALE2 0.18033688011112042f

// ---------------------------------------------------------------------------
// SESSION NOTES:
//  R1/R2: 8-phase 256^2 gemm8 port ran at 63 µs vs gemm_bt's 50 µs on the
//   same shapes (MfmaUtil 15% vs 19%); inline-asm ds_read + fence fix changed
//   NOTHING (alias-drain theory falsified). gemm8 path abandoned.
//  R3: 64x64 coalesced prep transposes: total 330 -> 325.5 (prep near its
//   ~100MB traffic floor now).
//  R4 (this): QKV epilogue surgery. QKV = slowest dispatch every iter
//   (50.4 µs = 515 TF vs ~850 for FF shapes on the same structure). Fix 1:
//   V-region r-quad stores pack to one 8B store (phi permute keeps r=0..3
//   consecutive in sp). Fix 2: region = bxs%3 interleave so V blocks spread
//   across all XCDs (was: all V on odd XCDs -> tail imbalance).
// ---------------------------------------------------------------------------
// prep: blocks 0..4095 cast x->bf16; 4096..5119 four 1024^2 transposes
// (64x64 tiles); 5120..6143 w1; 6144..7167 w2; 7168 mask->bf16.
__global__ __launch_bounds__(256) void prep_kernel(
    const float* __restrict__ x, unsigned short* __restrict__ XB,
    const float* __restrict__ wq, const float* __restrict__ wk,
    const float* __restrict__ wv, const float* __restrict__ wo,
    unsigned short* __restrict__ WQKV, unsigned short* __restrict__ WOT,
    const float* __restrict__ w1, unsigned short* __restrict__ W1T,
    const float* __restrict__ w2, unsigned short* __restrict__ W2T,
    const int* __restrict__ mask, unsigned short* __restrict__ MB) {
  const int bid = blockIdx.x;
  const int t = threadIdx.x;
  if (bid >= 7168) {  // mask -> bf16 0/1
    const int i0 = t * 16;
#pragma unroll
    for (int j = 0; j < 16; ++j) MB[i0 + j] = mask[i0 + j] ? 0x3F80 : 0;
    return;
  }
  if (bid < 4096) {  // cast x (pair-packed hw cvt)
    const int i = (bid * 256 + t) * 4;
    floatx4 v = *(const floatx4*)(x + i);
    union { uint32_t u[2]; ushort4v v4; } o;
    o.u[0] = pkbf(v[0], v[1]);
    o.u[1] = pkbf(v[2], v[3]);
    *(ushort4v*)(XB + i) = o.v4;
    return;
  }
  // 64x64 transpose tiles
  const float* in;
  unsigned short* out;
  int K, N, bx, by;
  if (bid < 5120) {  // wq/wk/wv/wo (1024^2 each, 256 tiles each)
    const int b2 = bid - 4096, z = b2 >> 8, bb = b2 & 255;
    in = (z == 0) ? wq : (z == 1) ? wk : (z == 2) ? wv : wo;
    out = (z == 3) ? WOT : WQKV + (size_t)z * 1024 * 1024;
    K = 1024; N = 1024; bx = bb & 15; by = bb >> 4;
  } else if (bid < 6144) {  // w1 [1024][4096] -> W1T [4096][1024]
    const int b3 = bid - 5120;
    in = w1; out = W1T; K = 1024; N = 4096; bx = b3 & 63; by = b3 >> 6;
  } else {  // w2 [4096][1024] -> W2T [1024][4096]
    const int b4 = bid - 6144;
    in = w2; out = W2T; K = 4096; N = 1024; bx = b4 & 15; by = b4 >> 4;
  }
  __shared__ float tile[64][65];  // tile[k][n]; 65-pad -> bank = (k + n) % 32
  const int n0 = bx * 64, k0 = by * 64;
  const int rl = t >> 4, c4 = (t & 15) * 4;  // load: 16 rows/pass x 64 cols
#pragma unroll
  for (int p = 0; p < 4; ++p) {
    const int r = rl + 16 * p;
    const floatx4 v = *(const floatx4*)(in + (size_t)(k0 + r) * N + n0 + c4);
#pragma unroll
    for (int j = 0; j < 4; ++j) tile[r][c4 + j] = v[j];
  }
  __syncthreads();
  const int rw = t >> 3, c8 = (t & 7) * 8;   // write: 32 rows/pass x 64 cols
#pragma unroll
  for (int p = 0; p < 2; ++p) {
    const int row = rw + 32 * p;             // output n-row
    union { unsigned short h[8]; short8 s8; } o;
#pragma unroll
    for (int j = 0; j < 8; ++j) o.h[j] = f2bf(tile[c8 + j][row]);
    *(short8*)(out + (size_t)(n0 + row) * K + k0 + c8) = o.s8;
  }
}

// ---------------------------------------------------------------------------
// GEMM: C = A[M,K] @ BT[N,K]^T (bf16 in, fp32 acc), BM=BN=128, BK=64, 256 thr.
// 16x16x32 MFMA, 4x4 acc/wave; __launch_bounds__(256,3) -> 3 blocks/CU.
// XCD RECTANGLE SWIZZLE: rectangles (nx/2 x ny/4) per XCD minimize per-XCD
// L2 footprint. LDS A/B each stored as TWO stacked 32-K panels of 64-B rows.
// SK: split-K (blockIdx.z; slice0->C0, slice1->C1).
// EPI: 2 = bias + fast GELU -> bf16
//      4 = bf16 partial store (split-K; bias added downstream in LN)
//      5 = fused QKV epilogue, REGION-INTERLEAVED (R4): region = bxs%3
//          (0 -> Q*QSCALE2 (C0); 1 -> K (C1); 2 -> V*mask, per-head-
//          transposed [bh][64][2048], keys phi-permuted, r-quad packed
//          8B stores (C2)). Interleave spreads V-epilogue cost across XCDs.
template <int EPI, int SK>
__global__ __launch_bounds__(256, 3) void gemm_bt_kernel(
    const unsigned short* __restrict__ A, const unsigned short* __restrict__ BT,
    const float* __restrict__ bias, void* __restrict__ C0, void* __restrict__ C1,
    void* __restrict__ C2, int M, int N, int K, const int* __restrict__ msk) {
  __shared__ __align__(16) unsigned short As[128 * 64];   // 2 panels x 8KB
  __shared__ __align__(16) unsigned short Bs[128 * 64];
  const int tid = threadIdx.x;
  const int w = tid >> 6, l = tid & 63;
  const int lq = l >> 4, lr = l & 15;

  int bxs, bys;
  {  // 2x4 XCD rectangle swizzle (perf-only; any mapping is correct)
    const int nx = gridDim.x, ny = gridDim.y;
    const int f = blockIdx.y * nx + blockIdx.x;
    const int xcd = f & 7, s = f >> 3;
    const int q = nx >> 1, p = ny >> 2;     // rect = q cols x p rows
    bxs = (xcd & 1) * q + (s % q);
    bys = (xcd >> 1) * p + (s / q);
  }
  const int m0 = bys * 128;
  // EPI==5: region-interleaved column mapping (R4). n0 stays the GLOBAL
  // column base so staging/compute are untouched; region = n0>>10 still holds.
  const int region = (EPI == 5) ? (bxs % 3) : 0;
  const int n0 = (EPI == 5) ? (region * 1024 + (bxs / 3) * 128) : (bxs * 128);
  const int wm = (w >> 1) * 64, wn = (w & 1) * 64;
  const int r_a = l >> 2;            // row within 16-row chunk
  const int colb = (l & 3) * 8;      // col (8 bf16 = 16B)
  const int kslice = K / SK;
  const int kbeg = kslice * blockIdx.z;

  // V-row mask, 16 packed bits (loads overlap the K-loop staging)
  uint32_t mbits = 0xFFFFu;
  if (EPI == 5 && region == 2) {
    mbits = 0;
#pragma unroll
    for (int mt = 0; mt < 4; ++mt) {
      const int4 m4 = *(const int4*)(msk + m0 + wm + mt * 16 + lq * 4);
      mbits |= (m4.x ? 1u : 0u) << (mt * 4);
      mbits |= (m4.y ? 1u : 0u) << (mt * 4 + 1);
      mbits |= (m4.z ? 1u : 0u) << (mt * 4 + 2);
      mbits |= (m4.w ? 1u : 0u) << (mt * 4 + 3);
    }
  }

  floatx4 acc[4][4];
  const floatx4 fz = {0.f, 0.f, 0.f, 0.f};
#pragma unroll
  for (int mt = 0; mt < 4; ++mt)
#pragma unroll
    for (int nt = 0; nt < 4; ++nt) acc[mt][nt] = fz;

  for (int k0 = kbeg; k0 < kbeg + kslice; k0 += 64) {
    __syncthreads();
#pragma unroll
    for (int p = 0; p < 2; ++p) {
#pragma unroll
      for (int i = 0; i < 2; ++i) {
        const int c = w * 2 + i;
        load_lds_128(A + (size_t)(m0 + c * 16 + r_a) * K + k0 + p * 32 + colb,
                     (char*)As + p * 8192 + c * 1024);
        load_lds_128(BT + (size_t)(n0 + c * 16 + r_a) * K + k0 + p * 32 + colb,
                     (char*)Bs + p * 8192 + c * 1024);
      }
    }
    __syncthreads();
#pragma unroll
    for (int p = 0; p < 2; ++p) {
      short8 af[4], bf[4];
#pragma unroll
      for (int mt = 0; mt < 4; ++mt)
        af[mt] = *(const short8*)((const char*)As + p * 8192 + (wm + mt * 16 + lr) * 64 + lq * 16);
#pragma unroll
      for (int nt = 0; nt < 4; ++nt)
        bf[nt] = *(const short8*)((const char*)Bs + p * 8192 + (wn + nt * 16 + lr) * 64 + lq * 16);
#pragma unroll
      for (int mt = 0; mt < 4; ++mt)
#pragma unroll
        for (int nt = 0; nt < 4; ++nt)
          acc[mt][nt] = MFMA16(af[mt], bf[nt], acc[mt][nt]);
    }
  }

  void* Cp = (SK > 1 && blockIdx.z) ? C1 : C0;
  // epilogue: C row = quad*4+reg, col = lane&15
#pragma unroll
  for (int mt = 0; mt < 4; ++mt) {
#pragma unroll
    for (int nt = 0; nt < 4; ++nt) {
      const int n = n0 + wn + nt * 16 + lr;
      if (EPI == 5 && region == 2) {
        // V region: r-quad packs into ONE 8B store. s0 4-aligned => u0&3==0,
        // no carry into phi bits => sp(r) = spb + r, consecutive.
        const int nn = n - 2048;
        const int hh = nn >> 6, d = nn & 63;
        const int s0 = m0 + wm + mt * 16 + lq * 4;
        const int bidx = s0 >> 11, si = s0 & 2047;
        const int u0 = si & 31;
        const int spb = (si & ~31) | (((u0 >> 4) & 1) << 2) | (((u0 >> 2) & 3) << 3);
        float vv[4];
#pragma unroll
        for (int r = 0; r < 4; ++r)
          vv[r] = ((mbits >> (mt * 4 + r)) & 1u) ? acc[mt][nt][r] : 0.f;
        union { uint32_t u[2]; ushort4v v4; } o;
        o.u[0] = pkbf(vv[0], vv[1]);
        o.u[1] = pkbf(vv[2], vv[3]);
        *(ushort4v*)((unsigned short*)C2 +
                     ((size_t)((bidx * 16 + hh) * 64 + d)) * 2048 + spb) = o.v4;
        continue;
      }
      float bval = 0.f;
      if (EPI == 2) bval = bias[n];
#pragma unroll
      for (int r = 0; r < 4; ++r) {
        const int m = m0 + wm + mt * 16 + lq * 4 + r;
        float v = acc[mt][nt][r];
        if (EPI == 4) {
          ((unsigned short*)Cp)[(size_t)m * N + n] = f2bf(v);
        } else if (EPI == 2) {
          ((unsigned short*)C0)[(size_t)m * N + n] = f2bf(fast_gelu(v + bval));
        } else {  // EPI == 5, region 0/1
          if (region == 0) {
            ((unsigned short*)C0)[(size_t)m * 1024 + n] = f2bf(v * QSCALE2);
          } else {
            ((unsigned short*)C1)[(size_t)m * 1024 + (n - 1024)] = f2bf(v);
          }
        }
      }
    }
  }
}

// ---------------------------------------------------------------------------
// Flash attention: S=2048, Dk=64. Q PRE-SCALED by 0.125*log2e (exp2 domain).
// FIXED-SHIFT softmax + TRANSPOSED-SCORE register pipeline (S^T = K·Q^T;
// C/D fragment is directly the PV A-operand under phi; V pre-permuted so the
// V B-fragment is one ds_read_b128). Q-tile 128 rows/block: K/V fragment
// reads shared across two q-groups per wave (halves LDS read traffic).
// XCD head-grouping: xcd owns 4 heads. LDS 32 KB. 512 blocks.
__global__ __launch_bounds__(256, 2) void flash_kernel(
    const unsigned short* __restrict__ Q, const unsigned short* __restrict__ Kg,
    const unsigned short* __restrict__ VT, const unsigned short* __restrict__ MB,
    unsigned short* __restrict__ ctx) {
  __shared__ __align__(16) unsigned short Ks[128 * 64];    // [key][d] / Q stage, swizzled
  __shared__ __align__(16) unsigned short VTs[64 * 128];   // [d][key'], swizzled

  const int tid = threadIdx.x, w = tid >> 6, l = tid & 63;
  const int lq = l >> 4, lr = l & 15;
  const int lin = blockIdx.x;
  const int xcd = lin & 7, slot = lin >> 3;     // 64 slots per XCD
  const int bh = xcd * 4 + (slot >> 4);         // 4 heads per XCD
  const int b = bh >> 4, h = bh & 15;
  const int q0 = (slot & 15) * 128;

  const unsigned short* Qp = Q + (size_t)(b * 2048 + q0) * 1024 + h * 64;
  const unsigned short* Kp = Kg + (size_t)(b * 2048) * 1024 + h * 64;
  const unsigned short* VTp = VT + (size_t)bh * 64 * 2048;
  const unsigned short* mbp = MB + b * 2048;

  {  // stage Q [128][64] once through Ks (16KB: 16 chunks, 4 per wave)
    const int rq = l >> 3, cs = l & 7;
#pragma unroll
    for (int i = 0; i < 4; ++i) {
      const int c = w * 4 + i;
      load_lds_128(Qp + (size_t)(c * 8 + rq) * 1024 + cs * 8, (char*)Ks + c * 1024);
    }
  }
  __syncthreads();
  short8 qf[2][2];  // [qg][kstep]; lane holds Q[q0+w*32+qg*16+lr][d=lq*8+..]
#pragma unroll
  for (int qg = 0; qg < 2; ++qg) {
    qf[qg][0] = *(const short8*)((const char*)Ks + (w * 32 + qg * 16 + lr) * 128 + lq * 16);
    qf[qg][1] = *(const short8*)((const char*)Ks + (w * 32 + qg * 16 + lr) * 128 + 64 + lq * 16);
  }
  __syncthreads();  // Q consumed; Ks reused for K tiles

  const floatx4 fz = {0.f, 0.f, 0.f, 0.f};
  floatx4 o[2][4];
#pragma unroll
  for (int qg = 0; qg < 2; ++qg)
#pragma unroll
    for (int nt = 0; nt < 4; ++nt) o[qg][nt] = fz;
  floatx4 l_acc[2] = {fz, fz};

  const int krow = l >> 3, kslot = l & 7;   // Ks staging: 8 rows / 1KB chunk
  const int vrow = l >> 4, vslot = l & 15;  // VTs staging: 4 rows / 1KB chunk

  for (int kb = 0; kb < 2048; kb += 128) {
    if (kb) __syncthreads();
#pragma unroll
    for (int i = 0; i < 4; ++i) {
      const int c4 = w * 4 + i;
      {  // Ks rows c4*8..+7; slot kslot holds logical chunk kslot^(row&7)
        const int row = c4 * 8 + krow;
        const int cc = kslot ^ (row & 7);
        load_lds_128(Kp + (size_t)(kb + row) * 1024 + cc * 8, (char*)Ks + c4 * 1024);
      }
      {  // VTs rows c4*4..+3; slot vslot holds logical chunk vslot^(row&15)
        const int row = c4 * 4 + vrow;
        const int cc = vslot ^ (row & 15);
        load_lds_128(VTp + (size_t)row * 2048 + kb + cc * 8, (char*)VTs + c4 * 1024);
      }
    }
    // mask fragments for the 4 PV windows (already in phi key order)
    short8 mf[4];
#pragma unroll
    for (int t = 0; t < 4; ++t) {
      const short4v ma = *(const short4v*)(mbp + kb + t * 32 + lq * 4);
      const short4v mb2 = *(const short4v*)(mbp + kb + t * 32 + 16 + lq * 4);
      mf[t] = short8{ma[0], ma[1], ma[2], ma[3], mb2[0], mb2[1], mb2[2], mb2[3]};
    }
    __syncthreads();

    // two halves of 64 keys each: 4 score-groups -> 2 PV windows
#pragma unroll
    for (int h2 = 0; h2 < 2; ++h2) {
      // S^T for both q-groups; K fragment reads SHARED across qg
      floatx4 s[2][4];
#pragma unroll
      for (int gg = 0; gg < 4; ++gg) {
        const int g = h2 * 4 + gg;
        const char* rowp = (const char*)Ks + (g * 16 + lr) * 128;
        short8 k0 = *(const short8*)(rowp + ((lq) ^ (lr & 7)) * 16);
        short8 k1 = *(const short8*)(rowp + ((4 + lq) ^ (lr & 7)) * 16);
#pragma unroll
        for (int qg = 0; qg < 2; ++qg) {
          floatx4 t = MFMA16(k0, qf[qg][0], fz);
          s[qg][gg] = MFMA16(k1, qf[qg][1], t);
        }
      }
      // p = exp2(score), hw-packed to bf16 A-fragments (phi key order)
      short8 pf[2][2];  // [qg][tt]
#pragma unroll
      for (int qg = 0; qg < 2; ++qg)
#pragma unroll
        for (int tt = 0; tt < 2; ++tt) {
          const floatx4 sL = s[qg][tt * 2], sH = s[qg][tt * 2 + 1];
          union { uint32_t u[4]; short8 s8; } pk;
          pk.u[0] = pkbf(EXP2(sL[0]), EXP2(sL[1]));
          pk.u[1] = pkbf(EXP2(sL[2]), EXP2(sL[3]));
          pk.u[2] = pkbf(EXP2(sH[0]), EXP2(sH[1]));
          pk.u[3] = pkbf(EXP2(sH[2]), EXP2(sH[3]));
          pf[qg][tt] = pk.s8;
        }
      // PV: windows t = h2*2 + tt; V fragment reads SHARED across qg
#pragma unroll
      for (int tt = 0; tt < 2; ++tt) {
        const int t = h2 * 2 + tt;
        l_acc[0] = MFMA16(pf[0][tt], mf[t], l_acc[0]);
        l_acc[1] = MFMA16(pf[1][tt], mf[t], l_acc[1]);
#pragma unroll
        for (int nt = 0; nt < 4; ++nt) {
          const int d = nt * 16 + lr;
          short8 vf = *(const short8*)((const char*)VTs + d * 256 +
                                       (((t * 4 + lq) ^ (d & 15)) * 16));
          o[0][nt] = MFMA16(pf[0][tt], vf, o[0][nt]);
          o[1][nt] = MFMA16(pf[1][tt], vf, o[1][nt]);
        }
      }
    }
  }

  // epilogue: q = q0 + w*32 + qg*16 + lq*4 + r, d = nt*16 + lr
#pragma unroll
  for (int qg = 0; qg < 2; ++qg)
#pragma unroll
    for (int r = 0; r < 4; ++r) {
      const float inv = 1.0f / l_acc[qg][r];
      const int q = q0 + w * 32 + qg * 16 + lq * 4 + r;
#pragma unroll
      for (int nt = 0; nt < 4; ++nt)
        ctx[(size_t)(b * 2048 + q) * 1024 + h * 64 + nt * 16 + lr] = f2bf(o[qg][nt][r] * inv);
    }
}

// ---------------------------------------------------------------------------
// fused residual + dual bf16-partial sum + bias + LayerNorm over rows of 1024.
// v = res + y0 + y1 + bias; out = LN(v)*gamma + beta.
template <int RESBF, int OUTBF>
__global__ __launch_bounds__(256) void ln2_kernel(
    const void* __restrict__ res, const unsigned short* __restrict__ y0,
    const unsigned short* __restrict__ y1, const float* __restrict__ bias,
    const float* __restrict__ gamma, const float* __restrict__ beta,
    void* __restrict__ outp) {
  const int row = blockIdx.x, t = threadIdx.x;
  const size_t base = (size_t)row * 1024 + t * 4;
  float v[4];
  if (RESBF) {
    ushort4v r4 = *(const ushort4v*)((const unsigned short*)res + base);
#pragma unroll
    for (int j = 0; j < 4; ++j) v[j] = bf2f(r4[j]);
  } else {
    floatx4 r4 = *(const floatx4*)((const float*)res + base);
#pragma unroll
    for (int j = 0; j < 4; ++j) v[j] = r4[j];
  }
  const ushort4v a4 = *(const ushort4v*)(y0 + base);
  const ushort4v b4v = *(const ushort4v*)(y1 + base);
  const floatx4 bi4 = *(const floatx4*)(bias + t * 4);
  float s = 0.f, ss = 0.f;
#pragma unroll
  for (int j = 0; j < 4; ++j) {
    v[j] += bf2f(a4[j]) + bf2f(b4v[j]) + bi4[j];
    s += v[j];
    ss += v[j] * v[j];
  }
#pragma unroll
  for (int off = 1; off < 64; off <<= 1) {
    s += __shfl_xor(s, off);
    ss += __shfl_xor(ss, off);
  }
  __shared__ float red[8];
  const int w = t >> 6;
  if ((t & 63) == 0) { red[w] = s; red[4 + w] = ss; }
  __syncthreads();
  s = red[0] + red[1] + red[2] + red[3];
  ss = red[4] + red[5] + red[6] + red[7];
  const float mean = s * (1.0f / 1024.0f);
  const float var = ss * (1.0f / 1024.0f) - mean * mean;
  const float rstd = rsqrtf(var + 1e-6f);
  const floatx4 g4 = *(const floatx4*)(gamma + t * 4);
  const floatx4 be4 = *(const floatx4*)(beta + t * 4);
  if (OUTBF) {
    union { uint32_t u[2]; ushort4v v4; } o;
    o.u[0] = pkbf((v[0] - mean) * rstd * g4[0] + be4[0],
                  (v[1] - mean) * rstd * g4[1] + be4[1]);
    o.u[1] = pkbf((v[2] - mean) * rstd * g4[2] + be4[2],
                  (v[3] - mean) * rstd * g4[3] + be4[3]);
    *(ushort4v*)((unsigned short*)outp + base) = o.v4;
  } else {
    floatx4 o;
#pragma unroll
    for (int j = 0; j < 4; ++j) o[j] = (v[j] - mean) * rstd * g4[j] + be4[j];
    *(floatx4*)((float*)outp + base) = o;
  }
}

// ---------------------------------------------------------------------------
extern "C" void kernel_launch(void* const* d_in, const int* in_sizes, int n_in,
                              void* d_out, int out_size, void* d_ws, size_t ws_size,
                              hipStream_t stream) {
  (void)in_sizes; (void)n_in; (void)out_size; (void)ws_size;
  const float* x    = (const float*)d_in[0];
  const int*   mask = (const int*)d_in[1];
  const float* wq   = (const float*)d_in[2];
  const float* wk   = (const float*)d_in[3];
  const float* wv   = (const float*)d_in[4];
  const float* wo   = (const float*)d_in[5];
  const float* wo_b = (const float*)d_in[6];
  const float* w1   = (const float*)d_in[7];
  const float* b1   = (const float*)d_in[8];
  const float* w2   = (const float*)d_in[9];
  const float* b2   = (const float*)d_in[10];
  const float* g1   = (const float*)d_in[11];
  const float* be1  = (const float*)d_in[12];
  const float* g2   = (const float*)d_in[13];
  const float* be2  = (const float*)d_in[14];
  float* out = (float*)d_out;

  char* ws = (char*)d_ws;
  const size_t MBy = 1024ull * 1024ull;
  // phase-aliased workspace (80 MB):
  unsigned short* WQKV = (unsigned short*)(ws + 0 * MBy);   // 6MB  (dead after QKV gemm)
  unsigned short* WOT  = (unsigned short*)(ws + 6 * MBy);   // 2MB  (dead after WO gemm)
  unsigned short* W1T  = (unsigned short*)(ws + 8 * MBy);   // 8MB  (dead after FF1)
  unsigned short* W2T  = (unsigned short*)(ws + 16 * MBy);  // 8MB  (dead after FF2)
  unsigned short* XB   = (unsigned short*)(ws + 24 * MBy);  // 8MB  (dead after QKV)
  unsigned short* Qb   = (unsigned short*)(ws + 32 * MBy);  // 8MB  (dead after flash)
  unsigned short* Kb   = (unsigned short*)(ws + 40 * MBy);  // 8MB  (dead after flash)
  unsigned short* VTb  = (unsigned short*)(ws + 48 * MBy);  // 8MB  (dead after flash)
  unsigned short* CTX  = (unsigned short*)(ws + 56 * MBy);  // 8MB  (dead after WO gemm)
  unsigned short* ATT0 = (unsigned short*)(ws + 32 * MBy);  // 8MB bf16, over Qb
  unsigned short* ATT1 = (unsigned short*)(ws + 40 * MBy);  // 8MB bf16, over Kb
  unsigned short* Hb   = (unsigned short*)(ws + 24 * MBy);  // 8MB  over XB
  unsigned short* G1   = (unsigned short*)(ws + 32 * MBy);  // 32MB over ATT0/ATT1/VTb/CTX
  unsigned short* FF20 = (unsigned short*)(ws + 64 * MBy);  // 8MB bf16
  unsigned short* FF21 = (unsigned short*)(ws + 72 * MBy);  // 8MB bf16
  unsigned short* MB   = (unsigned short*)(ws + 78 * MBy);  // 8KB bf16 mask (inside FF21
                                                            // region; FF21 written after flash)

  // 1. prep: cast x + all 6 weight transposes (64x64 coalesced) + bf16 mask
  prep_kernel<<<7169, 256, 0, stream>>>(x, XB, wq, wk, wv, wo, WQKV, WOT,
                                        w1, W1T, w2, W2T, mask, MB);
  // 2. fused QKV projection: N=3072 -> 768 blocks; Q pre-scaled, V masked+permuted
  gemm_bt_kernel<5, 1><<<dim3(24, 32), 256, 0, stream>>>(
      XB, WQKV, nullptr, Qb, Kb, VTb, 4096, 3072, 1024, mask);
  // 3. attention (512 blocks, q-tile 128, XCD head-grouped)
  flash_kernel<<<512, 256, 0, stream>>>(Qb, Kb, VTb, MB, CTX);
  // 4. output projection, split-K=2 bf16 partials (bias folded into LN1)
  gemm_bt_kernel<4, 2><<<dim3(8, 32, 2), 256, 0, stream>>>(
      CTX, WOT, nullptr, ATT0, ATT1, nullptr, 4096, 1024, 1024, nullptr);
  // 5. LN1: h = LN(x + att0 + att1 + wo_b) -> bf16
  ln2_kernel<0, 1><<<4096, 256, 0, stream>>>(x, ATT0, ATT1, wo_b, g1, be1, Hb);
  // 6. FF1 + bias + fast GELU -> bf16
  gemm_bt_kernel<2, 1><<<dim3(32, 32), 256, 0, stream>>>(
      Hb, W1T, b1, G1, nullptr, nullptr, 4096, 4096, 1024, nullptr);
  // 7. FF2, split-K=2 bf16 partials (bias folded into LN2)
  gemm_bt_kernel<4, 2><<<dim3(8, 32, 2), 256, 0, stream>>>(
      G1, W2T, nullptr, FF20, FF21, nullptr, 4096, 1024, 4096, nullptr);
  // 8. LN2: out = LN(h + ff0 + ff1 + b2) -> fp32
  ln2_kernel<1, 0><<<4096, 256, 0, stream>>>(Hb, FF20, FF21, b2, g2, be2, out);
}